// Round 1
// baseline (122.520 us; speedup 1.0000x reference)
//
#include <hip/hip_runtime.h>
#include <hip/hip_bf16.h>

// Problem constants (fixed by reference)
#define BB  4
#define CC  64      // input channels
#define NN  4096    // W*H
#define CF  32      // f/g channels (CH/2)
#define CHN 64      // h channels

typedef __attribute__((ext_vector_type(8))) __bf16 bf16x8;
typedef __attribute__((ext_vector_type(4))) __bf16 bf16x4;
typedef __attribute__((ext_vector_type(4))) float floatx4;

// clamp to [-60,60]; also kills NaN (v_max/v_min return the non-NaN operand)
__device__ __forceinline__ float clamp60(float v) {
    return fminf(fmaxf(v, -60.f), 60.f);
}
__device__ __forceinline__ float scrub(float v) {
    return fminf(fmaxf(v, -1e30f), 1e30f);
}

// ---------------------------------------------------------------------------
// Kernel 1: 1x1 convs as MFMA GEMM (r14/r15-verified, verbatim; hv bf16).
// ---------------------------------------------------------------------------
__global__ __launch_bounds__(256) void prep_kernel(
    const float* __restrict__ x, const float* __restrict__ y,
    const float* __restrict__ Wf, const float* __restrict__ bfp,
    const float* __restrict__ Wg, const float* __restrict__ bgp,
    const float* __restrict__ Wh, const float* __restrict__ bhp,
    __bf16* __restrict__ fT, __bf16* __restrict__ gT, __bf16* __restrict__ hvb)
{
    __shared__ __align__(16) __bf16 wbf[128][72];
    __shared__ float sbias[128];

    const int t  = threadIdx.x;
    const int w  = t >> 6;
    const int l  = t & 63;
    const int lo = l & 15;
    const int q  = l >> 4;

    const int b   = blockIdx.x >> 6;
    const int nb  = blockIdx.x & 63;
    const int nn  = nb * 64 + w * 16 + lo;

    for (int i = t; i < 128 * CC; i += 256) {
        int row = i >> 6, c = i & 63;
        float wv;
        if (row < 32)      wv = Wf[(size_t)row * CC + c];
        else if (row < 64) wv = Wg[(size_t)(row - 32) * CC + c];
        else               wv = Wh[(size_t)(row - 64) * CC + c];
        wbf[row][c] = (__bf16)wv;
    }
    if (t < 128) {
        if (t < 32)      sbias[t] = bfp[t];
        else if (t < 64) sbias[t] = bgp[t - 32];
        else             sbias[t] = bhp[t - 64];
    }
    __syncthreads();

    const float* xb = x + (size_t)b * CC * NN;
    const float* yb = y + (size_t)b * CC * NN;
    bf16x8 bx[2], by[2];
    #pragma unroll
    for (int kh = 0; kh < 2; kh++) {
        #pragma unroll
        for (int j = 0; j < 8; j++) {
            int c = kh * 32 + q * 8 + j;
            bx[kh][j] = (__bf16)xb[(size_t)c * NN + nn];
            by[kh][j] = (__bf16)yb[(size_t)c * NN + nn];
        }
    }

    const floatx4 zero4 = {0.f, 0.f, 0.f, 0.f};
    #pragma unroll
    for (int ct = 0; ct < 8; ct++) {
        const bf16x8* src = (ct < 2) ? bx : by;
        floatx4 acc = zero4;
        #pragma unroll
        for (int kh = 0; kh < 2; kh++) {
            const bf16x8 a = *(const bf16x8*)&wbf[ct*16 + lo][kh*32 + q*8];
            acc = __builtin_amdgcn_mfma_f32_16x16x32_bf16(a, src[kh], acc, 0, 0, 0);
        }
        if (ct < 4) {
            bf16x4 pk;
            #pragma unroll
            for (int r = 0; r < 4; r++)
                pk[r] = (__bf16)(acc[r] + sbias[ct*16 + q*4 + r]);
            __bf16* dstbase = (ct < 2) ? fT : gT;
            int cho = (ct & 1) * 16;
            *(bf16x4*)&dstbase[((size_t)b * NN + nn) * CF + cho + q*4] = pk;
        } else {
            #pragma unroll
            for (int r = 0; r < 4; r++) {
                int ch = (ct - 4) * 16 + q*4 + r;
                hvb[((size_t)b * CHN + ch) * NN + nn] =
                    (__bf16)(acc[r] + sbias[64 + ch]);
            }
        }
    }
}

// ---------------------------------------------------------------------------
// Kernel 2: fused MFMA flash attention + merge + epilogue.
// Grid = BB*128: block = (b, 32-row m-tile). 512 threads = 8 waves = 8
// n-parities, each covering the SAME 32 rows. Occupancy: 2 blocks/CU x 8
// waves = 4 waves/SIMD (was 2) -> latency hiding is the whole point of this
// revision. Per wave-chunk (32m x 64n): 12 VMEM loads, 8 QK + 16 PV + 4
// rowsum MFMAs, no-max softmax (r15-verified, clamp +-60), wave-private pbf
// roundtrip (r8-proven fences). Row sums via MFMA against all-ones B
// fragment (replaces 256 v_adds + shfl reduce; denominator now uses the
// same bf16-rounded P as the numerator). Merge: parallel 8-slot f32 LDS
// reduce (stride-67 pad, conflict-free), 2 barriers, fused epilogue.
// LDS: union of pbf (36.9KB, loop phase) and merge slots (69.6KB, merge
// phase) -> 69,632 B/block, 2 blocks/CU.
// ---------------------------------------------------------------------------
__global__ __launch_bounds__(512, 4) void attn_kernel(
    const __bf16* __restrict__ fT, const __bf16* __restrict__ gT,
    const __bf16* __restrict__ hvb,
    const float* __restrict__ x, const float* __restrict__ gamma_p,
    float* __restrict__ out)
{
    // Time-sliced LDS union:
    //   loop phase : pbf [256][72] bf16  = 36,864 B  (8 wave-private 32-row P)
    //   merge phase: osum [8][32][67] f32 = 68,608 B + lsum [8][32] f32 = 1,024 B
    __shared__ __align__(16) char smem[8*32*67*4 + 8*32*4];
    __bf16 (*pbf)[72]     = (__bf16 (*)[72])smem;
    float  (*osum)[32][67] = (float (*)[32][67])smem;
    float* lsum = (float*)(smem + 8*32*67*4);

    const int t  = threadIdx.x;
    const int w  = t >> 6;                // wave = n-parity (0..7)
    const int l  = t & 63;
    const int lo = l & 15;
    const int q  = l >> 4;

    const int mg = blockIdx.x & 127;      // 32-row tile
    const int b  = blockIdx.x >> 7;
    const int m0 = mg * 32;

    const __bf16* fb = fT  + (size_t)b * NN * CF;
    const __bf16* gb = gT  + (size_t)b * NN * CF;
    const __bf16* hb = hvb + (size_t)b * CHN * NN;

    // A-fragments of g for the wave's 2 m-tiles (verified r6 pattern)
    bf16x8 ag[2];
    #pragma unroll
    for (int mt = 0; mt < 2; mt++)
        ag[mt] = *(const bf16x8*)(gb + (size_t)(m0 + mt*16 + lo) * CF + q * 8);

    // all-ones B fragment for MFMA row sums
    bf16x8 vone;
    #pragma unroll
    for (int j = 0; j < 8; j++) vone[j] = (__bf16)1.0f;

    const floatx4 zero4 = {0.f, 0.f, 0.f, 0.f};
    floatx4 oacc[2][4];                   // [mt][ct]: m=mt*16+q*4+r, ch=ct*16+lo
    #pragma unroll
    for (int mt = 0; mt < 2; mt++)
        #pragma unroll
        for (int ct = 0; ct < 4; ct++) oacc[mt][ct] = zero4;
    floatx4 lacc[2];                      // row sums: m=mt*16+q*4+r (col-invariant)
    #pragma unroll
    for (int mt = 0; mt < 2; mt++) lacc[mt] = zero4;

    for (int i = 0; i < 8; i++) {
        const int n0 = (8*i + w) * 64;

        // B-fragments (verified): f for QK, hv for PV
        bf16x8 bff[4];
        #pragma unroll
        for (int nt = 0; nt < 4; nt++)
            bff[nt] = *(const bf16x8*)(fb + (size_t)(n0 + nt*16 + lo) * CF + q * 8);
        bf16x8 bhh[4][2];
        #pragma unroll
        for (int ct = 0; ct < 4; ct++)
            #pragma unroll
            for (int jb = 0; jb < 2; jb++)
                bhh[ct][jb] = *(const bf16x8*)(hb + (size_t)(ct*16 + lo) * NN + n0 + jb*32 + q*8);

        // QK (verified r6): 2 mt x 4 nt
        #pragma unroll
        for (int mt = 0; mt < 2; mt++) {
            floatx4 s4[4];
            #pragma unroll
            for (int nt = 0; nt < 4; nt++)
                s4[nt] = __builtin_amdgcn_mfma_f32_16x16x32_bf16(ag[mt], bff[nt], zero4, 0, 0, 0);

            // no-max softmax (r15-verified): exp, P -> wave-private pbf rows
            #pragma unroll
            for (int nt = 0; nt < 4; nt++)
                #pragma unroll
                for (int r = 0; r < 4; r++)
                    pbf[w*32 + mt*16 + q*4 + r][nt*16 + lo] =
                        (__bf16)__expf(clamp60(s4[nt][r]));
        }
        asm volatile("s_waitcnt lgkmcnt(0)" ::: "memory");

        bf16x8 ap[2][2];
        #pragma unroll
        for (int mt = 0; mt < 2; mt++)
            #pragma unroll
            for (int jb = 0; jb < 2; jb++)
                ap[mt][jb] = *(const bf16x8*)&pbf[w*32 + mt*16 + lo][jb*32 + q*8];
        asm volatile("s_waitcnt lgkmcnt(0)" ::: "memory");

        // row sums via MFMA with all-ones B (matrix pipe is underused)
        #pragma unroll
        for (int mt = 0; mt < 2; mt++)
            #pragma unroll
            for (int jb = 0; jb < 2; jb++)
                lacc[mt] = __builtin_amdgcn_mfma_f32_16x16x32_bf16(
                    ap[mt][jb], vone, lacc[mt], 0, 0, 0);

        // PV (verified r7): 2 mt x 4 ct x 2 jb
        #pragma unroll
        for (int mt = 0; mt < 2; mt++)
            #pragma unroll
            for (int ct = 0; ct < 4; ct++)
                #pragma unroll
                for (int jb = 0; jb < 2; jb++)
                    oacc[mt][ct] = __builtin_amdgcn_mfma_f32_16x16x32_bf16(
                        ap[mt][jb], bhh[ct][jb], oacc[mt][ct], 0, 0, 0);
    }

    // ---- parallel merge across the 8 parity waves
    __syncthreads();   // all waves done reading pbf before osum overwrites it
    #pragma unroll
    for (int mt = 0; mt < 2; mt++) {
        #pragma unroll
        for (int ct = 0; ct < 4; ct++)
            #pragma unroll
            for (int r = 0; r < 4; r++)
                osum[w][mt*16 + q*4 + r][ct*16 + lo] = oacc[mt][ct][r];
        if (lo == 0)
            #pragma unroll
            for (int r = 0; r < 4; r++)
                lsum[w*32 + mt*16 + q*4 + r] = lacc[mt][r];
    }
    __syncthreads();

    // ---- 8-slot reduce + fused epilogue: out = gamma * osum/lsum + x
    const float gam = gamma_p[0];
    const int m  = t & 31;          // coalesced across lanes
    const int cb = t >> 5;          // 0..15
    float lt = 0.f;
    #pragma unroll
    for (int s = 0; s < 8; s++) lt += lsum[s*32 + m];
    const float inv = 1.f / lt;
    #pragma unroll
    for (int it = 0; it < 4; it++) {
        const int ch = it*16 + cb;
        float acc = 0.f;
        #pragma unroll
        for (int s = 0; s < 8; s++) acc += osum[s][m][ch];
        size_t gi = ((size_t)b * CHN + ch) * NN + m0 + m;
        float ov = scrub(acc * inv);
        out[gi] = gam * ov + x[gi];
    }
}

// ---------------------------------------------------------------------------
extern "C" void kernel_launch(void* const* d_in, const int* in_sizes, int n_in,
                              void* d_out, int out_size, void* d_ws, size_t ws_size,
                              hipStream_t stream)
{
    const float* x     = (const float*)d_in[0];
    const float* y     = (const float*)d_in[1];
    const float* Wf    = (const float*)d_in[2];
    const float* bf    = (const float*)d_in[3];
    const float* Wg    = (const float*)d_in[4];
    const float* bg    = (const float*)d_in[5];
    const float* Wh    = (const float*)d_in[6];
    const float* bh    = (const float*)d_in[7];
    const float* gamma = (const float*)d_in[8];
    float* out = (float*)d_out;

    __bf16* wsb = (__bf16*)d_ws;
    __bf16* fT  = wsb;                                // [4][4096][32] bf16 = 1 MB
    __bf16* gT  = fT + (size_t)BB * NN * CF;          // 1 MB
    __bf16* hvb = gT + (size_t)BB * NN * CF;          // [4][64][4096] bf16 = 2 MB
    // total 4 MB of ws

    prep_kernel<<<dim3(BB * 64), dim3(256), 0, stream>>>(
        x, y, Wf, bf, Wg, bg, Wh, bh, fT, gT, hvb);
    attn_kernel<<<dim3(BB * 128), dim3(512), 0, stream>>>(
        fT, gT, hvb, x, gamma, out);
}

// Round 2
// 103.329 us; speedup vs baseline: 1.1857x; 1.1857x over previous
//
#include <hip/hip_runtime.h>
#include <hip/hip_bf16.h>

// Problem constants (fixed by reference)
#define BB  4
#define CC  64      // input channels
#define NN  4096    // W*H
#define CF  32      // f/g channels (CH/2)
#define CHN 64      // h channels

typedef __attribute__((ext_vector_type(8))) __bf16 bf16x8;
typedef __attribute__((ext_vector_type(4))) __bf16 bf16x4;
typedef __attribute__((ext_vector_type(4))) float floatx4;

// clamp to [-60,60]; also kills NaN (v_max/v_min return the non-NaN operand)
__device__ __forceinline__ float clamp60(float v) {
    return fminf(fmaxf(v, -60.f), 60.f);
}
__device__ __forceinline__ float scrub(float v) {
    return fminf(fmaxf(v, -1e30f), 1e30f);
}

// ---------------------------------------------------------------------------
// Kernel 1: 1x1 convs as MFMA GEMM (r14/r15-verified, verbatim; hv bf16).
// ---------------------------------------------------------------------------
__global__ __launch_bounds__(256) void prep_kernel(
    const float* __restrict__ x, const float* __restrict__ y,
    const float* __restrict__ Wf, const float* __restrict__ bfp,
    const float* __restrict__ Wg, const float* __restrict__ bgp,
    const float* __restrict__ Wh, const float* __restrict__ bhp,
    __bf16* __restrict__ fT, __bf16* __restrict__ gT, __bf16* __restrict__ hvb)
{
    __shared__ __align__(16) __bf16 wbf[128][72];
    __shared__ float sbias[128];

    const int t  = threadIdx.x;
    const int w  = t >> 6;
    const int l  = t & 63;
    const int lo = l & 15;
    const int q  = l >> 4;

    const int b   = blockIdx.x >> 6;
    const int nb  = blockIdx.x & 63;
    const int nn  = nb * 64 + w * 16 + lo;

    for (int i = t; i < 128 * CC; i += 256) {
        int row = i >> 6, c = i & 63;
        float wv;
        if (row < 32)      wv = Wf[(size_t)row * CC + c];
        else if (row < 64) wv = Wg[(size_t)(row - 32) * CC + c];
        else               wv = Wh[(size_t)(row - 64) * CC + c];
        wbf[row][c] = (__bf16)wv;
    }
    if (t < 128) {
        if (t < 32)      sbias[t] = bfp[t];
        else if (t < 64) sbias[t] = bgp[t - 32];
        else             sbias[t] = bhp[t - 64];
    }
    __syncthreads();

    const float* xb = x + (size_t)b * CC * NN;
    const float* yb = y + (size_t)b * CC * NN;
    bf16x8 bx[2], by[2];
    #pragma unroll
    for (int kh = 0; kh < 2; kh++) {
        #pragma unroll
        for (int j = 0; j < 8; j++) {
            int c = kh * 32 + q * 8 + j;
            bx[kh][j] = (__bf16)xb[(size_t)c * NN + nn];
            by[kh][j] = (__bf16)yb[(size_t)c * NN + nn];
        }
    }

    const floatx4 zero4 = {0.f, 0.f, 0.f, 0.f};
    #pragma unroll
    for (int ct = 0; ct < 8; ct++) {
        const bf16x8* src = (ct < 2) ? bx : by;
        floatx4 acc = zero4;
        #pragma unroll
        for (int kh = 0; kh < 2; kh++) {
            const bf16x8 a = *(const bf16x8*)&wbf[ct*16 + lo][kh*32 + q*8];
            acc = __builtin_amdgcn_mfma_f32_16x16x32_bf16(a, src[kh], acc, 0, 0, 0);
        }
        if (ct < 4) {
            bf16x4 pk;
            #pragma unroll
            for (int r = 0; r < 4; r++)
                pk[r] = (__bf16)(acc[r] + sbias[ct*16 + q*4 + r]);
            __bf16* dstbase = (ct < 2) ? fT : gT;
            int cho = (ct & 1) * 16;
            *(bf16x4*)&dstbase[((size_t)b * NN + nn) * CF + cho + q*4] = pk;
        } else {
            #pragma unroll
            for (int r = 0; r < 4; r++) {
                int ch = (ct - 4) * 16 + q*4 + r;
                hvb[((size_t)b * CHN + ch) * NN + nn] =
                    (__bf16)(acc[r] + sbias[64 + ch]);
            }
        }
    }
}

// ---------------------------------------------------------------------------
// Kernel 2: fused MFMA flash attention + merge + epilogue.
// r2 geometry: grid = BB*64 (1 block/CU): block = (b, 64-row m-tile).
// 512 threads = 8 waves = 8 n-parities; EACH WAVE covers all 64 rows
// (4 m-tiles, oacc[4][4]). Rationale (r1 post-mortem): doubling occupancy
// at constant per-CU L2 traffic gave 0% — time tracks per-CU line traffic,
// not TLP. 64-row blocks halve total f/hv re-reads: 393 MB -> 196 MB of
// L2 lines per dispatch. Per wave-iter: 12 VMEM loads now feed 2x MFMA
// (16 QK + 8 rowsum + 32 PV). All verified dataflow (fragment patterns,
// no-max softmax clamp +-60, wave-private pbf roundtrip fences) unchanged.
// Merge: 8 parity slots x 64 rows, parallel reduce, bit-identical
// summation order to r1. LDS union: pbf 73.7KB (loop) / osum+lsum 139.3KB
// (merge) -> 139,264 B, 1 block/CU, 8 waves = 2 waves/SIMD (TLP proven
// irrelevant in r1). __launch_bounds__(512,2) -> 256-VGPR budget for the
// ~180-reg live set, no spill.
// ---------------------------------------------------------------------------
__global__ __launch_bounds__(512, 2) void attn_kernel(
    const __bf16* __restrict__ fT, const __bf16* __restrict__ gT,
    const __bf16* __restrict__ hvb,
    const float* __restrict__ x, const float* __restrict__ gamma_p,
    float* __restrict__ out)
{
    // Time-sliced LDS union:
    //   loop phase : pbf [512][72] bf16   = 73,728 B (8 wave-private 64-row P)
    //   merge phase: osum [8][64][67] f32 = 137,216 B + lsum [8][64] f32 = 2,048 B
    __shared__ __align__(16) char smem[8*64*67*4 + 8*64*4];
    __bf16 (*pbf)[72]      = (__bf16 (*)[72])smem;
    float  (*osum)[64][67] = (float (*)[64][67])smem;
    float* lsum = (float*)(smem + 8*64*67*4);

    const int t  = threadIdx.x;
    const int w  = t >> 6;                // wave = n-parity (0..7)
    const int l  = t & 63;
    const int lo = l & 15;
    const int q  = l >> 4;

    const int mg = blockIdx.x & 63;       // 64-row tile
    const int b  = blockIdx.x >> 6;
    const int m0 = mg * 64;

    const __bf16* fb = fT  + (size_t)b * NN * CF;
    const __bf16* gb = gT  + (size_t)b * NN * CF;
    const __bf16* hb = hvb + (size_t)b * CHN * NN;

    // A-fragments of g for the wave's 4 m-tiles (verified r6 pattern)
    bf16x8 ag[4];
    #pragma unroll
    for (int mt = 0; mt < 4; mt++)
        ag[mt] = *(const bf16x8*)(gb + (size_t)(m0 + mt*16 + lo) * CF + q * 8);

    // all-ones B fragment for MFMA row sums
    bf16x8 vone;
    #pragma unroll
    for (int j = 0; j < 8; j++) vone[j] = (__bf16)1.0f;

    const floatx4 zero4 = {0.f, 0.f, 0.f, 0.f};
    floatx4 oacc[4][4];                   // [mt][ct]: m=mt*16+q*4+r, ch=ct*16+lo
    #pragma unroll
    for (int mt = 0; mt < 4; mt++)
        #pragma unroll
        for (int ct = 0; ct < 4; ct++) oacc[mt][ct] = zero4;
    floatx4 lacc[4];                      // row sums: m=mt*16+q*4+r (col-invariant)
    #pragma unroll
    for (int mt = 0; mt < 4; mt++) lacc[mt] = zero4;

    for (int i = 0; i < 8; i++) {
        const int n0 = (8*i + w) * 64;

        // B-fragments (verified): f for QK, hv for PV — 12 loads feed 56 MFMAs
        bf16x8 bff[4];
        #pragma unroll
        for (int nt = 0; nt < 4; nt++)
            bff[nt] = *(const bf16x8*)(fb + (size_t)(n0 + nt*16 + lo) * CF + q * 8);
        bf16x8 bhh[4][2];
        #pragma unroll
        for (int ct = 0; ct < 4; ct++)
            #pragma unroll
            for (int jb = 0; jb < 2; jb++)
                bhh[ct][jb] = *(const bf16x8*)(hb + (size_t)(ct*16 + lo) * NN + n0 + jb*32 + q*8);

        // QK (verified r6): 4 mt x 4 nt
        #pragma unroll
        for (int mt = 0; mt < 4; mt++) {
            floatx4 s4[4];
            #pragma unroll
            for (int nt = 0; nt < 4; nt++)
                s4[nt] = __builtin_amdgcn_mfma_f32_16x16x32_bf16(ag[mt], bff[nt], zero4, 0, 0, 0);

            // no-max softmax (r15-verified): exp, P -> wave-private pbf rows
            #pragma unroll
            for (int nt = 0; nt < 4; nt++)
                #pragma unroll
                for (int r = 0; r < 4; r++)
                    pbf[w*64 + mt*16 + q*4 + r][nt*16 + lo] =
                        (__bf16)__expf(clamp60(s4[nt][r]));
        }
        asm volatile("s_waitcnt lgkmcnt(0)" ::: "memory");

        bf16x8 ap[4][2];
        #pragma unroll
        for (int mt = 0; mt < 4; mt++)
            #pragma unroll
            for (int jb = 0; jb < 2; jb++)
                ap[mt][jb] = *(const bf16x8*)&pbf[w*64 + mt*16 + lo][jb*32 + q*8];
        asm volatile("s_waitcnt lgkmcnt(0)" ::: "memory");

        // row sums via MFMA with all-ones B (matrix pipe is underused)
        #pragma unroll
        for (int mt = 0; mt < 4; mt++)
            #pragma unroll
            for (int jb = 0; jb < 2; jb++)
                lacc[mt] = __builtin_amdgcn_mfma_f32_16x16x32_bf16(
                    ap[mt][jb], vone, lacc[mt], 0, 0, 0);

        // PV (verified r7): 4 mt x 4 ct x 2 jb
        #pragma unroll
        for (int mt = 0; mt < 4; mt++)
            #pragma unroll
            for (int ct = 0; ct < 4; ct++)
                #pragma unroll
                for (int jb = 0; jb < 2; jb++)
                    oacc[mt][ct] = __builtin_amdgcn_mfma_f32_16x16x32_bf16(
                        ap[mt][jb], bhh[ct][jb], oacc[mt][ct], 0, 0, 0);
    }

    // ---- parallel merge across the 8 parity waves
    __syncthreads();   // all waves done reading pbf before osum overwrites it
    #pragma unroll
    for (int mt = 0; mt < 4; mt++) {
        #pragma unroll
        for (int ct = 0; ct < 4; ct++)
            #pragma unroll
            for (int r = 0; r < 4; r++)
                osum[w][mt*16 + q*4 + r][ct*16 + lo] = oacc[mt][ct][r];
        if (lo == 0)
            #pragma unroll
            for (int r = 0; r < 4; r++)
                lsum[w*64 + mt*16 + q*4 + r] = lacc[mt][r];
    }
    __syncthreads();

    // ---- 8-slot reduce + fused epilogue: out = gamma * osum/lsum + x
    const float gam = gamma_p[0];
    const int m  = t & 63;          // coalesced across lanes (full wave = 64 m)
    const int cb = t >> 6;          // 0..7
    float lt = 0.f;
    #pragma unroll
    for (int s = 0; s < 8; s++) lt += lsum[s*64 + m];
    const float inv = 1.f / lt;
    #pragma unroll
    for (int it = 0; it < 8; it++) {
        const int ch = it*8 + cb;
        float acc = 0.f;
        #pragma unroll
        for (int s = 0; s < 8; s++) acc += osum[s][m][ch];
        size_t gi = ((size_t)b * CHN + ch) * NN + m0 + m;
        float ov = scrub(acc * inv);
        out[gi] = gam * ov + x[gi];
    }
}

// ---------------------------------------------------------------------------
extern "C" void kernel_launch(void* const* d_in, const int* in_sizes, int n_in,
                              void* d_out, int out_size, void* d_ws, size_t ws_size,
                              hipStream_t stream)
{
    const float* x     = (const float*)d_in[0];
    const float* y     = (const float*)d_in[1];
    const float* Wf    = (const float*)d_in[2];
    const float* bf    = (const float*)d_in[3];
    const float* Wg    = (const float*)d_in[4];
    const float* bg    = (const float*)d_in[5];
    const float* Wh    = (const float*)d_in[6];
    const float* bh    = (const float*)d_in[7];
    const float* gamma = (const float*)d_in[8];
    float* out = (float*)d_out;

    __bf16* wsb = (__bf16*)d_ws;
    __bf16* fT  = wsb;                                // [4][4096][32] bf16 = 1 MB
    __bf16* gT  = fT + (size_t)BB * NN * CF;          // 1 MB
    __bf16* hvb = gT + (size_t)BB * NN * CF;          // [4][64][4096] bf16 = 2 MB
    // total 4 MB of ws

    prep_kernel<<<dim3(BB * 64), dim3(256), 0, stream>>>(
        x, y, Wf, bf, Wg, bg, Wh, bh, fT, gT, hvb);
    attn_kernel<<<dim3(BB * 64), dim3(512), 0, stream>>>(
        fT, gT, hvb, x, gamma, out);
}